// Round 2
// baseline (1946.813 us; speedup 1.0000x reference)
//
#include <hip/hip_runtime.h>

#define B_ 4096
#define S_ 64
#define H_ 512

typedef _Float16 half8 __attribute__((ext_vector_type(8)));
typedef _Float16 half4 __attribute__((ext_vector_type(4)));
typedef float float4v __attribute__((ext_vector_type(4)));
typedef unsigned int uint4v __attribute__((ext_vector_type(4)));

// ---------------- weight fp32 -> fp16 conversion (once per launch) ----------------
__global__ void convert_weights_kernel(const float* __restrict__ Wr, const float* __restrict__ W,
                                       const float* __restrict__ Ur, const float* __restrict__ U,
                                       _Float16* __restrict__ out) {
    const float* src;
    switch (blockIdx.y) {
        case 0: src = Wr; break;
        case 1: src = W;  break;
        case 2: src = Ur; break;
        default: src = U; break;
    }
    int i = (blockIdx.x * blockDim.x + threadIdx.x) * 8;
    float4v a = *(const float4v*)(src + i);
    float4v b = *(const float4v*)(src + i + 4);
    half8 h;
    h[0] = (_Float16)a[0]; h[1] = (_Float16)a[1]; h[2] = (_Float16)a[2]; h[3] = (_Float16)a[3];
    h[4] = (_Float16)b[0]; h[5] = (_Float16)b[1]; h[6] = (_Float16)b[2]; h[7] = (_Float16)b[3];
    *(half8*)(out + (size_t)blockIdx.y * H_ * H_ + i) = h;
}

// ---------------- Phase 1: P[t][b][0:1024] = facts @ [Wr;W]^T + biases (fp16) ----------------
// facts is flat [262144][512] fp32 (M-row = b*64+t). Tile 128x128, BK=64, dbuf LDS 64KB -> 2 blocks/CU.
__global__ __launch_bounds__(256, 2)
void gemm_p_kernel(const float* __restrict__ facts, const _Float16* __restrict__ wAB,
                   const float* __restrict__ br, const float* __restrict__ bur,
                   const float* __restrict__ bw, _Float16* __restrict__ P)
{
    extern __shared__ _Float16 sm[]; // 2 x (A 128x64 + B 128x64) = 32768 halves = 64 KB
    const int tid = threadIdx.x;
    const int lane = tid & 63;
    const int wid = tid >> 6;
    const int l15 = lane & 15;
    const int l4  = lane >> 4;
    const int wm = wid >> 1, wn = wid & 1;
    const int bid = blockIdx.x;
    const int idx = bid & 63;                 // supertile: 8 m-tiles x 8 n-tiles
    const int mt = (bid >> 6) * 8 + (idx & 7);
    const int nt = idx >> 3;
    const int m0 = mt * 128, n0 = nt * 128;

    float4v acc[4][4];
#pragma unroll
    for (int m = 0; m < 4; ++m)
#pragma unroll
        for (int n = 0; n < 4; ++n) acc[m][n] = (float4v){0.f, 0.f, 0.f, 0.f};

    float4v sf[8];
    uint4v  swv[4];
    const int f_row = wid * 32 + l4;          // + j*4
    const int f_col = l15 * 4;
    const int b_row = wid * 32 + (lane >> 3); // + j*8
    const int b_chk = lane & 7;

    auto issue = [&](int kk) {
        const int k0 = kk * 64;
#pragma unroll
        for (int j = 0; j < 8; ++j)
            sf[j] = *(const float4v*)(facts + (size_t)(m0 + f_row + j * 4) * H_ + k0 + f_col);
#pragma unroll
        for (int j = 0; j < 4; ++j)
            swv[j] = *(const uint4v*)(wAB + (size_t)(n0 + b_row + j * 8) * H_ + k0 + b_chk * 8);
    };
    auto stage = [&](int sel) {
        _Float16* bf = sm + sel * 16384;
        _Float16* bb = bf + 8192;
#pragma unroll
        for (int j = 0; j < 8; ++j) {
            int row = f_row + j * 4;
            half4 h;
            h[0] = (_Float16)sf[j][0]; h[1] = (_Float16)sf[j][1];
            h[2] = (_Float16)sf[j][2]; h[3] = (_Float16)sf[j][3];
            int c16 = (l15 >> 1) ^ (row & 7);
            *(half4*)&bf[row * 64 + c16 * 8 + (l15 & 1) * 4] = h;
        }
#pragma unroll
        for (int j = 0; j < 4; ++j) {
            int row = b_row + j * 8;
            *(uint4v*)&bb[row * 64 + ((b_chk ^ (row & 7)) << 3)] = swv[j];
        }
    };
    auto compute = [&](int sel) {
        const _Float16* bf = sm + sel * 16384;
        const _Float16* bb = bf + 8192;
#pragma unroll
        for (int s = 0; s < 2; ++s) {
            const int kc = s * 4 + l4;
            half8 fa[4], wb[4];
#pragma unroll
            for (int m = 0; m < 4; ++m) {
                int row = wm * 64 + m * 16 + l15;
                fa[m] = *(const half8*)&bf[row * 64 + ((kc ^ (row & 7)) << 3)];
            }
#pragma unroll
            for (int n = 0; n < 4; ++n) {
                int row = wn * 64 + n * 16 + l15;
                wb[n] = *(const half8*)&bb[row * 64 + ((kc ^ (row & 7)) << 3)];
            }
#pragma unroll
            for (int m = 0; m < 4; ++m)
#pragma unroll
                for (int n = 0; n < 4; ++n)
                    acc[m][n] = __builtin_amdgcn_mfma_f32_16x16x32_f16(fa[m], wb[n], acc[m][n], 0, 0, 0);
        }
    };

    issue(0);
#pragma unroll
    for (int kk = 0; kk < 8; ++kk) {
        stage(kk & 1);
        if (kk + 1 < 8) issue(kk + 1);
        __syncthreads();
        compute(kk & 1);
    }

#pragma unroll
    for (int n = 0; n < 4; ++n) {
        const int col = n0 + wn * 64 + n * 16 + l15;
        const float bias = (col < H_) ? (br[col] + bur[col]) : bw[col - H_];
#pragma unroll
        for (int m = 0; m < 4; ++m)
#pragma unroll
            for (int r = 0; r < 4; ++r) {
                int rowl = wm * 64 + m * 16 + l4 * 4 + r;     // 0..127
                int grow = m0 + rowl;
                P[((size_t)(rowl & 63) * B_ + (grow >> 6)) * 1024 + col] = (_Float16)(acc[m][n][r] + bias);
            }
    }
}

// ---------------- Phase 2: recurrent step (2 families: C@Ur^T, C@U^T) ----------------
// r = sigmoid(P1 + C@Ur^T); ht = tanh(P2 + r*(C@U^T + bu)); h = g*ht + (1-g)*C
// BM=128, BN=32, grid (32,16)=512 blocks -> 2 blocks/CU (48 KB LDS each).
template<bool LAST>
__global__ __launch_bounds__(256, 2)
void gru_step2_kernel(const _Float16* __restrict__ P, const float* __restrict__ G,
                      const _Float16* __restrict__ wf,  // [Wr,W,Ur,U]; Ur at +2*H*H, U at +3*H*H
                      const float* __restrict__ bu,
                      const _Float16* __restrict__ c_in, _Float16* __restrict__ c_out,
                      float* __restrict__ out32, int t)
{
    extern __shared__ _Float16 sm[]; // 2 x (C 128x64 = 8192 + W 2x32x64 = 4096) = 24576 halves = 48 KB
    const int tid = threadIdx.x;
    const int lane = tid & 63;
    const int wid = tid >> 6;
    const int l15 = lane & 15;
    const int l4  = lane >> 4;
    const int wm = wid >> 1, wn = wid & 1;
    const int b0 = blockIdx.x * 128;
    const int n0 = blockIdx.y * 32;

    float4v acc[2][4]; // [fam][m]  fam0=Ur, fam1=U
#pragma unroll
    for (int f = 0; f < 2; ++f)
#pragma unroll
        for (int m = 0; m < 4; ++m) acc[f][m] = (float4v){0.f, 0.f, 0.f, 0.f};

    uint4v scv[4], swv2[2];
    const int c_row = wid * 32 + (lane >> 3); // + j*8
    const int c_chk = lane & 7;

    auto issue = [&](int kk) {
        const int k0 = kk * 64;
#pragma unroll
        for (int j = 0; j < 4; ++j)
            scv[j] = *(const uint4v*)(c_in + (size_t)(b0 + c_row + j * 8) * H_ + k0 + c_chk * 8);
#pragma unroll
        for (int jj = 0; jj < 2; ++jj) {
            int q = tid * 2 + jj;
            int fam = q >> 8, row = (q >> 3) & 31, chk = q & 7;
            swv2[jj] = *(const uint4v*)(wf + (size_t)(2 + fam) * H_ * H_ + (size_t)(n0 + row) * H_ + k0 + chk * 8);
        }
    };
    auto stage = [&](int sel) {
        _Float16* bc  = sm + sel * 12288;
        _Float16* bwt = bc + 8192;
#pragma unroll
        for (int j = 0; j < 4; ++j) {
            int row = c_row + j * 8;
            *(uint4v*)&bc[row * 64 + ((c_chk ^ (row & 7)) << 3)] = scv[j];
        }
#pragma unroll
        for (int jj = 0; jj < 2; ++jj) {
            int q = tid * 2 + jj;
            int fam = q >> 8, row = (q >> 3) & 31, chk = q & 7;
            *(uint4v*)&bwt[(fam * 32 + row) * 64 + ((chk ^ (row & 7)) << 3)] = swv2[jj];
        }
    };
    auto compute = [&](int sel) {
        const _Float16* bc  = sm + sel * 12288;
        const _Float16* bwt = bc + 8192;
#pragma unroll
        for (int s = 0; s < 2; ++s) {
            const int kc = s * 4 + l4;
            half8 fc[4], wfr[2];
#pragma unroll
            for (int m = 0; m < 4; ++m) {
                int row = wm * 64 + m * 16 + l15;
                fc[m] = *(const half8*)&bc[row * 64 + ((kc ^ (row & 7)) << 3)];
            }
#pragma unroll
            for (int f = 0; f < 2; ++f) {
                int row = wn * 16 + l15;
                wfr[f] = *(const half8*)&bwt[(f * 32 + row) * 64 + ((kc ^ (row & 7)) << 3)];
            }
#pragma unroll
            for (int m = 0; m < 4; ++m) {
                acc[0][m] = __builtin_amdgcn_mfma_f32_16x16x32_f16(fc[m], wfr[0], acc[0][m], 0, 0, 0);
                acc[1][m] = __builtin_amdgcn_mfma_f32_16x16x32_f16(fc[m], wfr[1], acc[1][m], 0, 0, 0);
            }
        }
    };

    issue(0);
#pragma unroll
    for (int kk = 0; kk < 8; ++kk) {
        stage(kk & 1);
        if (kk + 1 < 8) issue(kk + 1);
        __syncthreads();
        compute(kk & 1);
    }

    // epilogue
    const int col = n0 + wn * 16 + l15;
    const float buv = bu[col];
    const _Float16* Pt = P + (size_t)t * B_ * 1024;
#pragma unroll
    for (int m = 0; m < 4; ++m) {
#pragma unroll
        for (int r = 0; r < 4; ++r) {
            const int row = b0 + wm * 64 + m * 16 + l4 * 4 + r;
            float p1 = (float)Pt[(size_t)row * 1024 + col];
            float p2 = (float)Pt[(size_t)row * 1024 + 512 + col];
            float apre = p1 + acc[0][m][r];
            float rg = 1.0f / (1.0f + __expf(-apre));
            float x = p2 + rg * (acc[1][m][r] + buv);
            float e2 = __expf(2.0f * x);
            float ht = 1.0f - 2.0f / (e2 + 1.0f);
            float g = G[(size_t)row * S_ + t];
            float cold = (float)c_in[(size_t)row * H_ + col];
            float h = g * ht + (1.0f - g) * cold;
            if (LAST) out32[(size_t)row * H_ + col] = h;
            else      c_out[(size_t)row * H_ + col] = (_Float16)h;
        }
    }
}

extern "C" void kernel_launch(void* const* d_in, const int* in_sizes, int n_in,
                              void* d_out, int out_size, void* d_ws, size_t ws_size,
                              hipStream_t stream) {
    const float* facts = (const float*)d_in[0];
    const float* G     = (const float*)d_in[1];
    const float* Wr    = (const float*)d_in[2];
    const float* br    = (const float*)d_in[3];
    const float* Ur    = (const float*)d_in[4];
    const float* bur   = (const float*)d_in[5];
    const float* W     = (const float*)d_in[6];
    const float* bw    = (const float*)d_in[7];
    const float* U     = (const float*)d_in[8];
    const float* bu    = (const float*)d_in[9];

    _Float16* wf16 = (_Float16*)d_ws;                 // 4*512*512 fp16 = 2 MB ([Wr,W,Ur,U])
    _Float16* c0   = wf16 + 4 * H_ * H_;              // 4 MB
    _Float16* c1   = c0 + (size_t)B_ * H_;            // 4 MB
    _Float16* P    = c1 + (size_t)B_ * H_;            // 64*4096*1024 fp16 = 512 MB

    hipMemsetAsync(c0, 0, (size_t)B_ * H_ * sizeof(_Float16), stream); // C0 = 0
    convert_weights_kernel<<<dim3(H_ * H_ / (256 * 8), 4), 256, 0, stream>>>(Wr, W, Ur, U, wf16);

    // Phase 1: 2048 m-tiles x 8 n-tiles, supertile-swizzled 1D grid
    gemm_p_kernel<<<16384, 256, 65536, stream>>>(facts, wf16, br, bur, bw, P);

    // Phase 2: 64 recurrent steps
    dim3 grid2(B_ / 128, H_ / 32); // 32 x 16 = 512 blocks
    _Float16* bufs[2] = {c0, c1};
    for (int t = 0; t < S_; ++t) {
        _Float16* cin  = bufs[t & 1];
        _Float16* cout = bufs[(t & 1) ^ 1];
        if (t == S_ - 1)
            gru_step2_kernel<true><<<grid2, 256, 49152, stream>>>(P, G, wf16, bu, cin, cout, (float*)d_out, t);
        else
            gru_step2_kernel<false><<<grid2, 256, 49152, stream>>>(P, G, wf16, bu, cin, cout, nullptr, t);
    }
}